// Round 1
// baseline (144.491 us; speedup 1.0000x reference)
//
#include <hip/hip_runtime.h>
#include <hip/hip_bf16.h>

// SupConLoss forward, fused flash-style: never materialize the 8192x8192 logits.
constexpr int B_SZ = 4096;
constexpr int N_SZ = 8192;   // B*V
constexpr int D_SZ = 128;
constexpr int CSPLIT = 8;            // column chunks (grid.y)
constexpr int CHUNK = N_SZ / CSPLIT; // 1024 cols per chunk

typedef __attribute__((ext_vector_type(8))) __bf16 bf16x8;
typedef __attribute__((ext_vector_type(4))) float f32x4;

// exp(dot/T) = exp2(dot * 1/(T*ln2));  T = 0.3
#define EXP2_SCALE 4.8089834f
// -(TEMPERATURE / BASE_TEMPERATURE)
#define NEG_RATIO (-(0.3f / 0.07f))

__device__ __forceinline__ unsigned short f2bf(float f) {
    unsigned u = __float_as_uint(f);
    u += 0x7FFFu + ((u >> 16) & 1u);   // round-to-nearest-even
    return (unsigned short)(u >> 16);
}

// features [B, V, D] f32  ->  Abf [N, D] bf16, view-major: row v*B+b = features[b, v, :]
__global__ __launch_bounds__(256) void prep_kernel(const float* __restrict__ feat,
                                                   unsigned short* __restrict__ Abf) {
    int t = blockIdx.x * 256 + threadIdx.x;  // 0 .. N*D/4-1 = 262143
    int n = t >> 5;                          // output row
    int q = (t & 31) << 2;                   // d offset (x4 vectorized)
    int b = n & (B_SZ - 1);
    int v = n >> 12;                         // n / B_SZ
    const float4 f = *reinterpret_cast<const float4*>(feat + (((size_t)b * 2 + v) << 7) + q);
    ushort4 o;
    o.x = f2bf(f.x); o.y = f2bf(f.y); o.z = f2bf(f.z); o.w = f2bf(f.w);
    *reinterpret_cast<ushort4*>(Abf + (((size_t)n) << 7) + q) = o;
}

// Each block: 64 rows (4 waves x 16 rows), one 1024-column chunk.
// Per wave: hoist A-fragments, sweep 16-wide column tiles, 4 MFMA (K=128) per tile,
// fused exp / diag-skip / label-mask epilogue, per-lane accumulation, one butterfly at end.
__global__ __launch_bounds__(256) void gram_kernel(const unsigned short* __restrict__ Abf,
                                                   const int* __restrict__ labels,
                                                   float* __restrict__ S_part,
                                                   float* __restrict__ P_part) {
    __shared__ int labCol[CHUNK];
    const int tid = threadIdx.x;
    const int col0 = blockIdx.y * CHUNK;
    for (int t = tid; t < CHUNK; t += 256)
        labCol[t] = labels[(col0 + t) & (B_SZ - 1)];
    __syncthreads();

    const int wave = tid >> 6;
    const int lane = tid & 63;
    const int grp  = lane >> 4;   // 0..3
    const int lc   = lane & 15;   // 0..15
    const int rowBase = blockIdx.x * 64 + wave * 16;
    const int myRow0  = rowBase + grp * 4;     // C/D rows of this lane: myRow0 .. +3

    // A fragments (frag element i at k = k0 + 8*grp + i), hoisted for all column tiles
    bf16x8 afrag[4];
    {
        const unsigned short* ap = Abf + ((size_t)(rowBase + lc) << 7) + grp * 8;
        afrag[0] = *reinterpret_cast<const bf16x8*>(ap);
        afrag[1] = *reinterpret_cast<const bf16x8*>(ap + 32);
        afrag[2] = *reinterpret_cast<const bf16x8*>(ap + 64);
        afrag[3] = *reinterpret_cast<const bf16x8*>(ap + 96);
    }
    int labRow[4];
#pragma unroll
    for (int r = 0; r < 4; ++r)
        labRow[r] = labels[(myRow0 + r) & (B_SZ - 1)];

    float s_sum[4] = {0.f, 0.f, 0.f, 0.f};
    float p_sum[4] = {0.f, 0.f, 0.f, 0.f};

    for (int j = 0; j < CHUNK; j += 16) {
        const int J = col0 + j;
        const unsigned short* bp = Abf + ((size_t)(J + lc) << 7) + grp * 8;
        f32x4 acc = {0.f, 0.f, 0.f, 0.f};
        acc = __builtin_amdgcn_mfma_f32_16x16x32_bf16(afrag[0], *reinterpret_cast<const bf16x8*>(bp),      acc, 0, 0, 0);
        acc = __builtin_amdgcn_mfma_f32_16x16x32_bf16(afrag[1], *reinterpret_cast<const bf16x8*>(bp + 32), acc, 0, 0, 0);
        acc = __builtin_amdgcn_mfma_f32_16x16x32_bf16(afrag[2], *reinterpret_cast<const bf16x8*>(bp + 64), acc, 0, 0, 0);
        acc = __builtin_amdgcn_mfma_f32_16x16x32_bf16(afrag[3], *reinterpret_cast<const bf16x8*>(bp + 96), acc, 0, 0, 0);

        const int col  = J + lc;
        const int labC = labCol[j + lc];
#pragma unroll
        for (int r = 0; r < 4; ++r) {
            const float dot = acc[r];                    // raw a_i . a_j  (logit = dot/T)
            const bool diag = (myRow0 + r) == col;
            const float e = exp2f(dot * EXP2_SCALE);
            s_sum[r] += diag ? 0.f : e;
            p_sum[r] += ((labRow[r] == labC) && !diag) ? dot : 0.f;
        }
    }

    // reduce across the 16 lanes (columns) of each group
#pragma unroll
    for (int m = 1; m < 16; m <<= 1) {
#pragma unroll
        for (int r = 0; r < 4; ++r) {
            s_sum[r] += __shfl_xor(s_sum[r], m);
            p_sum[r] += __shfl_xor(p_sum[r], m);
        }
    }
    if (lc == 0) {
        const size_t base = (size_t)blockIdx.y * N_SZ;
#pragma unroll
        for (int r = 0; r < 4; ++r) {
            S_part[base + myRow0 + r] = s_sum[r];
            P_part[base + myRow0 + r] = p_sum[r];
        }
    }
}

// Single block: label count, combine CSPLIT partials per row, log-sum, mean -> scalar.
__global__ __launch_bounds__(256) void final_kernel(const float* __restrict__ S_part,
                                                    const float* __restrict__ P_part,
                                                    const int* __restrict__ labels,
                                                    float* __restrict__ out) {
    __shared__ float redf[4];
    __shared__ int   redi[4];
    const int tid = threadIdx.x;

    int c = 0;
    for (int i = tid; i < B_SZ; i += 256) c += labels[i];
#pragma unroll
    for (int m = 1; m < 64; m <<= 1) c += __shfl_xor(c, m);
    if ((tid & 63) == 0) redi[tid >> 6] = c;
    __syncthreads();
    const int c1 = redi[0] + redi[1] + redi[2] + redi[3];

    float acc = 0.f;
    for (int i = tid; i < N_SZ; i += 256) {
        float S = 0.f, P = 0.f;
#pragma unroll
        for (int cix = 0; cix < CSPLIT; ++cix) {
            S += S_part[(size_t)cix * N_SZ + i];
            P += P_part[(size_t)cix * N_SZ + i];
        }
        const int lab = labels[i & (B_SZ - 1)];
        const int csame = lab ? c1 : (B_SZ - c1);
        const float n = (float)(2 * csame - 1);
        const float L = logf(S + 1e-8f);
        acc += (P * (1.0f / 0.3f) - n * L) / (n + 1e-8f);
    }
#pragma unroll
    for (int m = 1; m < 64; m <<= 1) acc += __shfl_xor(acc, m);
    if ((tid & 63) == 0) redf[tid >> 6] = acc;
    __syncthreads();
    if (tid == 0) {
        const float tot = redf[0] + redf[1] + redf[2] + redf[3];
        out[0] = tot * (NEG_RATIO / (float)N_SZ);
    }
}

extern "C" void kernel_launch(void* const* d_in, const int* in_sizes, int n_in,
                              void* d_out, int out_size, void* d_ws, size_t ws_size,
                              hipStream_t stream) {
    const float* feat  = (const float*)d_in[0];
    const int* labels  = (const int*)d_in[1];
    float* out = (float*)d_out;

    unsigned short* Abf = (unsigned short*)d_ws;                           // 2 MB
    float* S_part = (float*)((char*)d_ws + (size_t)N_SZ * D_SZ * 2);       // 256 KB
    float* P_part = S_part + (size_t)CSPLIT * N_SZ;                        // 256 KB

    prep_kernel<<<dim3(N_SZ * D_SZ / 4 / 256), dim3(256), 0, stream>>>(feat, Abf);
    gram_kernel<<<dim3(N_SZ / 64, CSPLIT), dim3(256), 0, stream>>>(Abf, labels, S_part, P_part);
    final_kernel<<<dim3(1), dim3(256), 0, stream>>>(S_part, P_part, labels, out);
}